// Round 6
// baseline (202.979 us; speedup 1.0000x reference)
//
#include <hip/hip_runtime.h>
#include <hip/hip_bf16.h>
#include <stdint.h>

typedef __attribute__((ext_vector_type(8))) _Float16 half8;
typedef __attribute__((ext_vector_type(4))) _Float16 half4;
typedef __attribute__((ext_vector_type(2))) __fp16 fp16x2;
typedef __attribute__((ext_vector_type(4))) float f32x4;
typedef __attribute__((ext_vector_type(16))) float f32x16;
typedef __attribute__((ext_vector_type(4))) float float4v;

#define DEVI static __device__ __forceinline__

constexpr int Bb = 16, Nn = 2048, Cc = 256, Dd = 256;

DEVI unsigned short f2h_bits(float f) {
  _Float16 h = (_Float16)f;
  union { _Float16 h; unsigned short u; } c;
  c.h = h;
  return c.u;
}

DEVI void gl_lds16(const void* gsrc, void* ldst) {
  __builtin_amdgcn_global_load_lds(
      (const __attribute__((address_space(1))) unsigned int*)gsrc,
      (__attribute__((address_space(3))) unsigned int*)ldst, 16, 0, 0);
}

DEVI f32x4 mfma16h(half8 a, half8 b, f32x4 c) {
  return __builtin_amdgcn_mfma_f32_16x16x32_f16(a, b, c, 0, 0, 0);
}
DEVI f32x16 mfma32h(half8 a, half8 b, f32x16 c) {
  return __builtin_amdgcn_mfma_f32_32x32x16_f16(a, b, c, 0, 0, 0);
}

DEVI unsigned int pkrtz(float a, float b) {
  union { fp16x2 h; unsigned int u; } c;
  c.h = __builtin_amdgcn_cvt_pkrtz(a, b);
  return c.u;
}

// ---------- kernel 0a: x (f32) -> xh (fp16) ----------
__global__ void k_split_x(const float* __restrict__ x, _Float16* __restrict__ xh) {
  int i = blockIdx.x * 256 + threadIdx.x;
  float4v v = reinterpret_cast<const float4v*>(x)[i];
  half4 h;
#pragma unroll
  for (int j = 0; j < 4; ++j) h[j] = (_Float16)v[j];
  reinterpret_cast<half4*>(xh)[i] = h;
}

// ---------- kernel 0b: W (f32) -> wh (fp16), [mat][d][c] ----------
__global__ void k_split_w(const float* __restrict__ wq, const float* __restrict__ wk,
                          const float* __restrict__ wv, _Float16* __restrict__ wh) {
  int i = blockIdx.x * 256 + threadIdx.x;
  int mat = i >> 16;
  int rem = i & 65535;
  const float* w = (mat == 0) ? wq : ((mat == 1) ? wk : wv);
  wh[(size_t)mat * 65536 + rem] = (_Float16)w[rem];
}

// ---------- kernel 1: QKV projection GEMM (fp16 in, f32 acc) ----------
__global__ __launch_bounds__(256, 2) void k_qkv(
    const _Float16* __restrict__ xh, const _Float16* __restrict__ wh,
    const float* __restrict__ bq, const float* __restrict__ bk, const float* __restrict__ bv,
    _Float16* __restrict__ qout, _Float16* __restrict__ kout, _Float16* __restrict__ vt) {
  __shared__ __align__(16) unsigned short smem[17408];

  const int tid = threadIdx.x;
  const int m0 = blockIdx.x * 128;
  const int n0 = blockIdx.y * 128;
  const int mat = blockIdx.z;
  const _Float16* wmat = wh + (size_t)mat * 65536;
  const int wave = tid >> 6, lane = tid & 63;
  const int wr = wave >> 1, wc = wave & 1;
  const int l15 = lane & 15, lq = lane >> 4;

  f32x4 zero4 = {0.f, 0.f, 0.f, 0.f};
  f32x4 acc[4][4];
#pragma unroll
  for (int a = 0; a < 4; ++a)
#pragma unroll
    for (int b2 = 0; b2 < 4; ++b2) acc[a][b2] = zero4;

  char* As = (char*)smem;
  char* Bs = (char*)smem + 16384;

  for (int kc = 0; kc < 4; ++kc) {
#pragma unroll
    for (int i = 0; i < 4; ++i) {
      int p = i * 4096 + tid * 16;
      int row = p >> 7;
      int src_in_row = (p & 127) ^ ((row & 7) << 4);
      const char* g = (const char*)(xh + (size_t)(m0 + row) * Cc + kc * 64) + src_in_row;
      gl_lds16(g, As + p);
    }
#pragma unroll
    for (int i = 0; i < 4; ++i) {
      int p = i * 4096 + tid * 16;
      int row = p >> 7;
      int src_in_row = (p & 127) ^ ((row & 7) << 4);
      const char* g = (const char*)(wmat + (size_t)(n0 + row) * Cc + kc * 64) + src_in_row;
      gl_lds16(g, Bs + p);
    }
    __syncthreads();
#pragma unroll
    for (int ks = 0; ks < 2; ++ks) {
      half8 af[4], bfr[4];
#pragma unroll
      for (int mf = 0; mf < 4; ++mf) {
        int row = wr * 64 + mf * 16 + l15;
        int byte = (row * 128 + ks * 64 + lq * 16) ^ ((row & 7) << 4);
        af[mf] = *(const half8*)(As + byte);
      }
#pragma unroll
      for (int nf = 0; nf < 4; ++nf) {
        int row = wc * 64 + nf * 16 + l15;
        int byte = (row * 128 + ks * 64 + lq * 16) ^ ((row & 7) << 4);
        bfr[nf] = *(const half8*)(Bs + byte);
      }
#pragma unroll
      for (int mf = 0; mf < 4; ++mf)
#pragma unroll
        for (int nf = 0; nf < 4; ++nf) acc[mf][nf] = mfma16h(af[mf], bfr[nf], acc[mf][nf]);
    }
    __syncthreads();
  }

  const float* bias = (mat == 0) ? bq : ((mat == 1) ? bk : bv);
  if (mat < 2) {
    _Float16* oo = (mat == 0) ? qout : kout;
#pragma unroll
    for (int nf = 0; nf < 4; ++nf) {
      int col = n0 + wc * 64 + nf * 16 + l15;
      float bval = bias[col];
#pragma unroll
      for (int mf = 0; mf < 4; ++mf) {
        int grow = m0 + wr * 64 + mf * 16 + lq * 4;
#pragma unroll
        for (int r = 0; r < 4; ++r)
          oo[(size_t)(grow + r) * Dd + col] = (_Float16)(acc[mf][nf][r] + bval);
      }
    }
  } else {
    __syncthreads();
#pragma unroll
    for (int nf = 0; nf < 4; ++nf) {
      int dl = wc * 64 + nf * 16 + l15;
      float bval = bias[n0 + dl];
#pragma unroll
      for (int mf = 0; mf < 4; ++mf) {
        int nl = wr * 64 + mf * 16 + lq * 4;
#pragma unroll
        for (int r = 0; r < 4; ++r) smem[dl * 136 + nl + r] = f2h_bits(acc[mf][nf][r] + bval);
      }
    }
    __syncthreads();
    const int bbat = m0 >> 11, tok0 = m0 & 2047;
#pragma unroll
    for (int pss = 0; pss < 8; ++pss) {
      int idx = pss * 256 + tid;
      int dl = idx >> 4;
      int cu = idx & 15;
      half8 vval = *(const half8*)((const char*)smem + dl * 272 + cu * 16);
      size_t off = ((size_t)bbat * Dd + n0 + dl) * Nn + tok0 + cu * 8;
      *(half8*)(vt + off) = vval;
    }
  }
}

// ---------- kernel 2: flash attention, 8 waves, 32x32 swapped-operand ----------
// 256 blocks (1/CU, XCD-pinned), 512 thr = 8 waves = 4 wq x 2 wk.
// Wave (wq,wk): S^T[32 keys (wk-half)][32 q (wq-group)] = mfma32(K_frag, Q_regs).
// Lane owns ONE q (l&31): softmax max/sum in-register + shfl_xor(32); P packed
// via cvt_pkrtz + quad exchange; PV: O^T = mfma32(V^T_frag, P) -> m,l,rescale
// all lane-local. wk-pair O partials combined once in epilogue via LDS.
__global__ __launch_bounds__(512, 2) void k_attn(
    const _Float16* __restrict__ qg, const _Float16* __restrict__ kin,
    const _Float16* __restrict__ vt, const int* __restrict__ vlen,
    float* __restrict__ out) {
  __shared__ __align__(16) char KV[2][65536];  // per buf: K 32KB | V 32KB
  __shared__ float mexch[8][32];
  __shared__ float lexch[8][32];

  const int tid = threadIdx.x;
  const int wave = tid >> 6, lane = tid & 63;
  const int l31 = lane & 31, h = lane >> 5;
  const int wq = wave >> 1, wk = wave & 1;
  const int id = blockIdx.x;
  const int g = id & 7;
  const int j = id >> 3;
  const int b = g + 8 * (j >> 4);  // XCD g owns batches {g, g+8}
  const int q0 = (j & 15) * 128;
  const int L = vlen[b];
  const bool uni = (L == 0);
  const int Lk = uni ? Nn : L;
  const int nt = (Lk + 63) >> 6;

  // Q regs: q = q0 + wq*32 + l31 (fixed per lane); d = kt*16 + h*8 + [0..8)
  const size_t qbase = ((size_t)b * Nn + q0 + wq * 32 + l31) * Dd;
  half8 qreg[16];
#pragma unroll
  for (int kt = 0; kt < 16; ++kt)
    qreg[kt] = *(const half8*)(qg + qbase + kt * 16 + h * 8);

  f32x16 acc[8];
#pragma unroll
  for (int dg = 0; dg < 8; ++dg)
#pragma unroll
    for (int r = 0; r < 16; ++r) acc[dg][r] = 0.f;
  float m = -__builtin_inff();
  float lsum = 0.f;

  const char* kbase = (const char*)(kin + (size_t)b * Nn * Dd);
  const char* vbase = (const char*)(vt + (size_t)b * Dd * Nn);

  // K LDS: [64 key][512B], 5-bit XOR slot swizzle (conflict-free for 32-row reads)
  // V LDS: d-quad interleaved [64 r][512B]: r=d>>2, logical col=(d&3)*128+k*2,
  //        5-bit XOR slot swizzle -> conflict-free A-operand reads.
  auto STAGE = [&](int buf, int t) {
    char* dst = (char*)KV[buf];
    const int k0 = t * 64;
#pragma unroll
    for (int i = 0; i < 4; ++i) {
      int p = i * 8192 + tid * 16;
      int row = p >> 9;
      int sl = ((p & 511) >> 4) ^ (row & 31);
      gl_lds16(kbase + (size_t)(k0 + row) * 512 + (sl << 4), dst + p);
    }
#pragma unroll
    for (int i = 0; i < 4; ++i) {
      int p = i * 8192 + tid * 16;
      int r = p >> 9;
      int sl = ((p & 511) >> 4) ^ (r & 31);
      int cl = sl << 4;
      int d = r * 4 + (cl >> 7);
      int kbyte = cl & 127;
      gl_lds16(vbase + (size_t)d * (Nn * 2) + (size_t)k0 * 2 + kbyte, dst + 32768 + p);
    }
  };

  STAGE(0, 0);

  for (int t = 0; t < nt; ++t) {
    const int cur = t & 1;
    if (t + 1 < nt) {
      STAGE(cur ^ 1, t + 1);
      asm volatile("s_waitcnt vmcnt(8)" ::: "memory");
    } else {
      asm volatile("s_waitcnt vmcnt(0)" ::: "memory");
    }
    asm volatile("s_barrier" ::: "memory");

    const char* Ks = (const char*)KV[cur];
    const char* Vs = (const char*)KV[cur] + 32768;
    const int k0 = t * 64;

    // S^T = K * Q^T : A = K frag (LDS), B = Q (regs). Lane: q-col = l31.
    f32x16 st;
#pragma unroll
    for (int r = 0; r < 16; ++r) st[r] = 0.f;
    if (!uni) {
      const int key = wk * 32 + l31;
      __builtin_amdgcn_s_setprio(1);
#pragma unroll
      for (int kt = 0; kt < 16; ++kt) {
        int byte = key * 512 + (((kt * 2 + h) ^ l31) << 4);
        half8 kf = *(const half8*)(Ks + byte);
        st = mfma32h(kf, qreg[kt], st);
      }
      __builtin_amdgcn_s_setprio(0);
      if (k0 + 64 > L) {
#pragma unroll
        for (int r = 0; r < 16; ++r) {
          int keyg = k0 + wk * 32 + (r & 3) + 8 * (r >> 2) + 4 * h;
          if (keyg >= L) st[r] = -1e6f;
        }
      }
    }

    // per-lane softmax (lane's q = l31; its 16 key-rows + pair-lane's 16)
    float pm = st[0];
#pragma unroll
    for (int r = 1; r < 16; ++r) pm = fmaxf(pm, st[r]);
    pm = fmaxf(pm, __shfl_xor(pm, 32));
    if (lane < 32) mexch[wave][lane] = pm;
    asm volatile("s_waitcnt lgkmcnt(0)\ns_barrier" ::: "memory");
    float pmo = mexch[wave ^ 1][l31];
    float mnew = fmaxf(m, fmaxf(pm, pmo));
    float scale = __expf(m - mnew);  // m=-inf -> 0
    m = mnew;
    float p[16];
    float psum = 0.f;
#pragma unroll
    for (int r = 0; r < 16; ++r) {
      p[r] = __expf(st[r] - mnew);
      psum += p[r];
    }
    lsum = lsum * scale + psum;

    // pack P (fp16 pairs) + lane-pair quad exchange -> B-operand frags
    unsigned int Qp[8];
#pragma unroll
    for (int i = 0; i < 8; ++i) Qp[i] = pkrtz(p[2 * i], p[2 * i + 1]);
    unsigned int y0 = __shfl_xor((int)(h ? Qp[0] : Qp[2]), 32);
    unsigned int y1 = __shfl_xor((int)(h ? Qp[1] : Qp[3]), 32);
    unsigned int y2 = __shfl_xor((int)(h ? Qp[4] : Qp[6]), 32);
    unsigned int y3 = __shfl_xor((int)(h ? Qp[5] : Qp[7]), 32);
    union { unsigned int u[4]; half8 v; } pa0, pa1;
    pa0.u[0] = h ? y0 : Qp[0];
    pa0.u[1] = h ? y1 : Qp[1];
    pa0.u[2] = h ? Qp[2] : y0;
    pa0.u[3] = h ? Qp[3] : y1;
    pa1.u[0] = h ? y2 : Qp[4];
    pa1.u[1] = h ? y3 : Qp[5];
    pa1.u[2] = h ? Qp[6] : y2;
    pa1.u[3] = h ? Qp[7] : y3;

    // rescale O^T (lane-local scalar scale)
#pragma unroll
    for (int dg = 0; dg < 8; ++dg)
#pragma unroll
      for (int r = 0; r < 16; ++r) acc[dg][r] *= scale;

    // PV: O^T += V^T * P^T.  A = V^T frag (LDS), B = P frag (regs).
    __builtin_amdgcn_s_setprio(1);
#pragma unroll
    for (int dg = 0; dg < 8; ++dg) {
      int r = dg * 8 + (l31 >> 2);
#pragma unroll
      for (int ks = 0; ks < 2; ++ks) {
        int slog = (l31 & 3) * 8 + wk * 4 + ks * 2 + h;
        half8 vf = *(const half8*)(Vs + r * 512 + ((slog ^ (r & 31)) << 4));
        acc[dg] = mfma32h(vf, ks ? pa1.v : pa0.v, acc[dg]);
      }
    }
    __builtin_amdgcn_s_setprio(0);

    asm volatile("s_barrier" ::: "memory");
  }

  // ---- epilogue ----
  // combine l across lane pair, then across wk pair
  lsum += __shfl_xor(lsum, 32);
  if (lane < 32) lexch[wave][lane] = lsum;
  asm volatile("s_waitcnt lgkmcnt(0)\ns_barrier" ::: "memory");
  float linv = 1.f / (lsum + lexch[wave ^ 1][l31]);

  // wk-pair O^T combine through LDS (write peer's dg-half, read own half)
  float* ob = (float*)KV;  // 128KB, reused
  const int ph0 = (wk ^ 1) * 4;
#pragma unroll
  for (int dg2 = 0; dg2 < 4; ++dg2) {
    int dg = ph0 + dg2;
#pragma unroll
    for (int r = 0; r < 16; ++r)
      ob[((wq * 8 + dg) * 16 + r) * 64 + lane] = acc[dg][r];
  }
  asm volatile("s_waitcnt lgkmcnt(0)\ns_barrier" ::: "memory");

  const size_t orow = (size_t)b * Nn + q0 + wq * 32 + l31;
#pragma unroll
  for (int dg2 = 0; dg2 < 4; ++dg2) {
    int dg = wk * 4 + dg2;
    float vfin[16];
#pragma unroll
    for (int r = 0; r < 16; ++r)
      vfin[r] = (acc[dg][r] + ob[((wq * 8 + dg) * 16 + r) * 64 + lane]) * linv;
#pragma unroll
    for (int qd = 0; qd < 4; ++qd) {
      float4v v4 = {vfin[qd * 4 + 0], vfin[qd * 4 + 1], vfin[qd * 4 + 2], vfin[qd * 4 + 3]};
      *(float4v*)(out + orow * Dd + dg * 32 + qd * 8 + h * 4) = v4;
    }
  }
}

// ---------- launch ----------
extern "C" void kernel_launch(void* const* d_in, const int* in_sizes, int n_in,
                              void* d_out, int out_size, void* d_ws, size_t ws_size,
                              hipStream_t stream) {
  const float* x = (const float*)d_in[0];
  const int* vlen = (const int*)d_in[1];
  const float* Wq = (const float*)d_in[2];
  const float* bq = (const float*)d_in[3];
  const float* Wk = (const float*)d_in[4];
  const float* bk = (const float*)d_in[5];
  const float* Wv = (const float*)d_in[6];
  const float* bv = (const float*)d_in[7];
  float* out = (float*)d_out;
  char* ws = (char*)d_ws;

  _Float16* qh = (_Float16*)(ws);
  _Float16* kk = (_Float16*)(ws + 16777216);
  _Float16* vt = (_Float16*)(ws + 33554432);
  _Float16* wh = (_Float16*)(ws + 50331648);
  _Float16* xh = (_Float16*)d_out;  // scratch; fully overwritten by k_attn

  k_split_x<<<8192, 256, 0, stream>>>(x, xh);
  k_split_w<<<768, 256, 0, stream>>>(Wq, Wk, Wv, wh);
  k_qkv<<<dim3(256, 2, 3), 256, 0, stream>>>(xh, wh, bq, bk, bv, qh, kk, vt);
  k_attn<<<256, 512, 0, stream>>>(qh, kk, vt, vlen, out);
}

// Round 7
// 118.249 us; speedup vs baseline: 1.7165x; 1.7165x over previous
//
#include <hip/hip_runtime.h>
#include <hip/hip_bf16.h>
#include <stdint.h>

typedef __attribute__((ext_vector_type(8))) _Float16 half8;
typedef __attribute__((ext_vector_type(4))) _Float16 half4;
typedef __attribute__((ext_vector_type(2))) __fp16 fp16x2;
typedef __attribute__((ext_vector_type(4))) float f32x4;
typedef __attribute__((ext_vector_type(16))) float f32x16;
typedef __attribute__((ext_vector_type(4))) float float4v;

#define DEVI static __device__ __forceinline__

constexpr int Bb = 16, Nn = 2048, Cc = 256, Dd = 256;

DEVI unsigned short f2h_bits(float f) {
  _Float16 h = (_Float16)f;
  union { _Float16 h; unsigned short u; } c;
  c.h = h;
  return c.u;
}

DEVI void gl_lds16(const void* gsrc, void* ldst) {
  __builtin_amdgcn_global_load_lds(
      (const __attribute__((address_space(1))) unsigned int*)gsrc,
      (__attribute__((address_space(3))) unsigned int*)ldst, 16, 0, 0);
}

DEVI f32x4 mfma16h(half8 a, half8 b, f32x4 c) {
  return __builtin_amdgcn_mfma_f32_16x16x32_f16(a, b, c, 0, 0, 0);
}
DEVI f32x16 mfma32h(half8 a, half8 b, f32x16 c) {
  return __builtin_amdgcn_mfma_f32_32x32x16_f16(a, b, c, 0, 0, 0);
}

DEVI unsigned int pkrtz(float a, float b) {
  union { fp16x2 h; unsigned int u; } c;
  c.h = __builtin_amdgcn_cvt_pkrtz(a, b);
  return c.u;
}

// ---------- kernel 0a: x (f32) -> xh (fp16) ----------
__global__ void k_split_x(const float* __restrict__ x, _Float16* __restrict__ xh) {
  int i = blockIdx.x * 256 + threadIdx.x;
  float4v v = reinterpret_cast<const float4v*>(x)[i];
  half4 h;
#pragma unroll
  for (int j = 0; j < 4; ++j) h[j] = (_Float16)v[j];
  reinterpret_cast<half4*>(xh)[i] = h;
}

// ---------- kernel 0b: W (f32) -> wh (fp16), [mat][d][c] ----------
__global__ void k_split_w(const float* __restrict__ wq, const float* __restrict__ wk,
                          const float* __restrict__ wv, _Float16* __restrict__ wh) {
  int i = blockIdx.x * 256 + threadIdx.x;
  int mat = i >> 16;
  int rem = i & 65535;
  const float* w = (mat == 0) ? wq : ((mat == 1) ? wk : wv);
  wh[(size_t)mat * 65536 + rem] = (_Float16)w[rem];
}

// ---------- kernel 1: QKV projection GEMM (fp16 in, f32 acc) ----------
__global__ __launch_bounds__(256, 2) void k_qkv(
    const _Float16* __restrict__ xh, const _Float16* __restrict__ wh,
    const float* __restrict__ bq, const float* __restrict__ bk, const float* __restrict__ bv,
    _Float16* __restrict__ qout, _Float16* __restrict__ kout, _Float16* __restrict__ vt) {
  __shared__ __align__(16) unsigned short smem[17408];

  const int tid = threadIdx.x;
  const int m0 = blockIdx.x * 128;
  const int n0 = blockIdx.y * 128;
  const int mat = blockIdx.z;
  const _Float16* wmat = wh + (size_t)mat * 65536;
  const int wave = tid >> 6, lane = tid & 63;
  const int wr = wave >> 1, wc = wave & 1;
  const int l15 = lane & 15, lq = lane >> 4;

  f32x4 zero4 = {0.f, 0.f, 0.f, 0.f};
  f32x4 acc[4][4];
#pragma unroll
  for (int a = 0; a < 4; ++a)
#pragma unroll
    for (int b2 = 0; b2 < 4; ++b2) acc[a][b2] = zero4;

  char* As = (char*)smem;
  char* Bs = (char*)smem + 16384;

  for (int kc = 0; kc < 4; ++kc) {
#pragma unroll
    for (int i = 0; i < 4; ++i) {
      int p = i * 4096 + tid * 16;
      int row = p >> 7;
      int src_in_row = (p & 127) ^ ((row & 7) << 4);
      const char* g = (const char*)(xh + (size_t)(m0 + row) * Cc + kc * 64) + src_in_row;
      gl_lds16(g, As + p);
    }
#pragma unroll
    for (int i = 0; i < 4; ++i) {
      int p = i * 4096 + tid * 16;
      int row = p >> 7;
      int src_in_row = (p & 127) ^ ((row & 7) << 4);
      const char* g = (const char*)(wmat + (size_t)(n0 + row) * Cc + kc * 64) + src_in_row;
      gl_lds16(g, Bs + p);
    }
    __syncthreads();
#pragma unroll
    for (int ks = 0; ks < 2; ++ks) {
      half8 af[4], bfr[4];
#pragma unroll
      for (int mf = 0; mf < 4; ++mf) {
        int row = wr * 64 + mf * 16 + l15;
        int byte = (row * 128 + ks * 64 + lq * 16) ^ ((row & 7) << 4);
        af[mf] = *(const half8*)(As + byte);
      }
#pragma unroll
      for (int nf = 0; nf < 4; ++nf) {
        int row = wc * 64 + nf * 16 + l15;
        int byte = (row * 128 + ks * 64 + lq * 16) ^ ((row & 7) << 4);
        bfr[nf] = *(const half8*)(Bs + byte);
      }
#pragma unroll
      for (int mf = 0; mf < 4; ++mf)
#pragma unroll
        for (int nf = 0; nf < 4; ++nf) acc[mf][nf] = mfma16h(af[mf], bfr[nf], acc[mf][nf]);
    }
    __syncthreads();
  }

  const float* bias = (mat == 0) ? bq : ((mat == 1) ? bk : bv);
  if (mat < 2) {
    _Float16* oo = (mat == 0) ? qout : kout;
#pragma unroll
    for (int nf = 0; nf < 4; ++nf) {
      int col = n0 + wc * 64 + nf * 16 + l15;
      float bval = bias[col];
#pragma unroll
      for (int mf = 0; mf < 4; ++mf) {
        int grow = m0 + wr * 64 + mf * 16 + lq * 4;
#pragma unroll
        for (int r = 0; r < 4; ++r)
          oo[(size_t)(grow + r) * Dd + col] = (_Float16)(acc[mf][nf][r] + bval);
      }
    }
  } else {
    __syncthreads();
#pragma unroll
    for (int nf = 0; nf < 4; ++nf) {
      int dl = wc * 64 + nf * 16 + l15;
      float bval = bias[n0 + dl];
#pragma unroll
      for (int mf = 0; mf < 4; ++mf) {
        int nl = wr * 64 + mf * 16 + lq * 4;
#pragma unroll
        for (int r = 0; r < 4; ++r) smem[dl * 136 + nl + r] = f2h_bits(acc[mf][nf][r] + bval);
      }
    }
    __syncthreads();
    const int bbat = m0 >> 11, tok0 = m0 & 2047;
#pragma unroll
    for (int pss = 0; pss < 8; ++pss) {
      int idx = pss * 256 + tid;
      int dl = idx >> 4;
      int cu = idx & 15;
      half8 vval = *(const half8*)((const char*)smem + dl * 272 + cu * 16);
      size_t off = ((size_t)bbat * Dd + n0 + dl) * Nn + tok0 + cu * 8;
      *(half8*)(vt + off) = vval;
    }
  }
}

// ---------- kernel 2: flash attention, 8 waves = 4 wq x 2 wk ----------
// QK^T: wave (wq,wk) computes S^T[keys wk*32..+32][32 q] (16 mfma32, swapped).
// Softmax: lane-local (q = l31) + wk-pair max/l exchange via LDS.
// P exchanged via LDS (B-frag layout); PV d-split: wave accumulates only
// d = wk*128..+128 -> acc 4 x f32x16 = 64 AGPR, no spill (round-6 bug).
// Epilogue: O through LDS transpose -> coalesced 1KB global stores.
__global__ __launch_bounds__(512, 2) void k_attn(
    const _Float16* __restrict__ qg, const _Float16* __restrict__ kin,
    const _Float16* __restrict__ vt, const int* __restrict__ vlen,
    float* __restrict__ out) {
  __shared__ __align__(16) char SMEM[149504];
  char* const KVb = SMEM;                                   // [2][65536]: K 32KB | V 32KB
  unsigned int* const PL = (unsigned int*)(SMEM + 131072);  // [4 wq][32 kp][32 q] u32
  float* const mex = (float*)(SMEM + 147456);               // [8][32]
  float* const lex = (float*)(SMEM + 148480);               // [8][32]

  const int tid = threadIdx.x;
  const int wave = tid >> 6, lane = tid & 63;
  const int l31 = lane & 31, h = lane >> 5;
  const int wq = wave >> 1, wk = wave & 1;
  const int id = blockIdx.x;
  const int g = id & 7;
  const int j = id >> 3;
  const int b = g + 8 * (j >> 4);  // XCD g owns batches {g, g+8}
  const int q0 = (j & 15) * 128;
  const int L = vlen[b];
  const bool uni = (L == 0);
  const int Lk = uni ? Nn : L;
  const int nt = (Lk + 63) >> 6;

  const char* kbase = (const char*)(kin + (size_t)b * Nn * Dd);
  const char* vbase = (const char*)(vt + (size_t)b * Dd * Nn);
  const char* qbase = (const char*)(qg + ((size_t)b * Nn + q0) * Dd);

  // K LDS: [64 key][512B], 5-bit XOR slot swizzle. V LDS: d-quad interleaved.
  auto STAGE = [&](int buf, int t) {
    char* dst = KVb + buf * 65536;
    const int k0 = t * 64;
#pragma unroll
    for (int i = 0; i < 4; ++i) {
      int p = i * 8192 + tid * 16;
      int row = p >> 9;
      int sl = ((p & 511) >> 4) ^ (row & 31);
      gl_lds16(kbase + (size_t)(k0 + row) * 512 + (sl << 4), dst + p);
    }
#pragma unroll
    for (int i = 0; i < 4; ++i) {
      int p = i * 8192 + tid * 16;
      int r = p >> 9;
      int sl = ((p & 511) >> 4) ^ (r & 31);
      int cl = sl << 4;
      int d = r * 4 + (cl >> 7);
      int kbyte = cl & 127;
      gl_lds16(vbase + (size_t)d * (Nn * 2) + (size_t)k0 * 2 + kbyte, dst + 32768 + p);
    }
  };

  // prologue: stage tile 0 into buf0, Q tile into buf1 (K-style layout)
  STAGE(0, 0);
#pragma unroll
  for (int i = 0; i < 8; ++i) {
    int p = i * 8192 + tid * 16;
    int row = p >> 9;
    int sl = ((p & 511) >> 4) ^ (row & 31);
    gl_lds16(qbase + (size_t)row * 512 + (sl << 4), KVb + 65536 + p);
  }
  asm volatile("s_waitcnt vmcnt(0)" ::: "memory");
  asm volatile("s_barrier" ::: "memory");

  // Q frags from LDS: q-row = wq*32 + l31, d = kt*16 + h*8 + [0..8)
  half8 qreg[16];
  {
    const int row = wq * 32 + l31;
#pragma unroll
    for (int kt = 0; kt < 16; ++kt) {
      int byte = row * 512 + (((kt * 2 + h) ^ (row & 31)) << 4);
      qreg[kt] = *(const half8*)(KVb + 65536 + byte);
    }
  }
  asm volatile("s_waitcnt lgkmcnt(0)" ::: "memory");
  asm volatile("s_barrier" ::: "memory");  // protect buf1 before loop staging

  f32x16 acc[4];
#pragma unroll
  for (int dg = 0; dg < 4; ++dg)
#pragma unroll
    for (int r = 0; r < 16; ++r) acc[dg][r] = 0.f;
  float m = -__builtin_inff();
  float lsum = 0.f;

  for (int t = 0; t < nt; ++t) {
    const int cur = t & 1;
    if (t + 1 < nt) {
      STAGE(cur ^ 1, t + 1);
      asm volatile("s_waitcnt vmcnt(8)" ::: "memory");
    } else {
      asm volatile("s_waitcnt vmcnt(0)" ::: "memory");
    }
    asm volatile("s_barrier" ::: "memory");  // A: tile t ready

    const char* Ks = KVb + cur * 65536;
    const char* Vs = Ks + 32768;
    const int k0 = t * 64;

    // S^T = K * Q^T : A = K frag (LDS rows wk*32..), B = Q regs. col q = l31.
    f32x16 st;
#pragma unroll
    for (int r = 0; r < 16; ++r) st[r] = 0.f;
    if (!uni) {
      const int key = wk * 32 + l31;
      __builtin_amdgcn_s_setprio(1);
#pragma unroll
      for (int kt = 0; kt < 16; ++kt) {
        int byte = key * 512 + (((kt * 2 + h) ^ l31) << 4);
        half8 kf = *(const half8*)(Ks + byte);
        st = mfma32h(kf, qreg[kt], st);
      }
      __builtin_amdgcn_s_setprio(0);
      if (k0 + 64 > L) {
#pragma unroll
        for (int r = 0; r < 16; ++r) {
          int keyg = k0 + wk * 32 + (r & 3) + 8 * (r >> 2) + 4 * h;
          if (keyg >= L) st[r] = -1e6f;
        }
      }
    }

    // partial max over own 32 keys (rows + pair-lane)
    float pm = st[0];
#pragma unroll
    for (int r = 1; r < 16; ++r) pm = fmaxf(pm, st[r]);
    pm = fmaxf(pm, __shfl_xor(pm, 32));
    if (lane < 32) mex[wave * 32 + lane] = pm;
    asm volatile("s_waitcnt lgkmcnt(0)\ns_barrier" ::: "memory");  // B
    float pmo = mex[(wave ^ 1) * 32 + l31];
    float mnew = fmaxf(m, fmaxf(pm, pmo));
    float scale = __expf(m - mnew);  // m=-inf -> 0
    m = mnew;
    float psum = 0.f;
#pragma unroll
    for (int r = 0; r < 16; ++r) {
      float p_ = __expf(st[r] - mnew);
      st[r] = p_;
      psum += p_;
    }
    lsum = lsum * scale + psum;

    // pack P pairs -> PL[wq][kp][q]  (key(i) = wk*32 + 8*(i>>1) + 2*(i&1) + 4h)
#pragma unroll
    for (int i = 0; i < 8; ++i) {
      unsigned int pk = pkrtz(st[2 * i], st[2 * i + 1]);
      int kp = wk * 16 + 4 * (i >> 1) + (i & 1) + 2 * h;
      PL[wq * 1024 + kp * 32 + l31] = pk;
    }
    asm volatile("s_waitcnt lgkmcnt(0)\ns_barrier" ::: "memory");  // C

    // read all-64-key P frags (B-operand: k = ks*16 + h*8 + j, col q = l31)
    union { unsigned int u[4]; half8 v; } pf0, pf1, pf2, pf3;
#pragma unroll
    for (int w = 0; w < 4; ++w) {
      pf0.u[w] = PL[wq * 1024 + (0 * 8 + h * 4 + w) * 32 + l31];
      pf1.u[w] = PL[wq * 1024 + (1 * 8 + h * 4 + w) * 32 + l31];
      pf2.u[w] = PL[wq * 1024 + (2 * 8 + h * 4 + w) * 32 + l31];
      pf3.u[w] = PL[wq * 1024 + (3 * 8 + h * 4 + w) * 32 + l31];
    }

    // rescale O^T (lane-local)
#pragma unroll
    for (int dg = 0; dg < 4; ++dg)
#pragma unroll
      for (int r = 0; r < 16; ++r) acc[dg][r] *= scale;

    // PV: O^T[d-half][32q] += V^T * P. A-row d = wk*128 + dg*32 + l31.
    __builtin_amdgcn_s_setprio(1);
#pragma unroll
    for (int dg = 0; dg < 4; ++dg) {
      int r = wk * 32 + dg * 8 + (l31 >> 2);
#pragma unroll
      for (int ks = 0; ks < 4; ++ks) {
        int slot = (l31 & 3) * 8 + ks * 2 + h;
        half8 vf = *(const half8*)(Vs + r * 512 + ((slot ^ (r & 31)) << 4));
        acc[dg] = mfma32h(vf, ks == 0 ? pf0.v : (ks == 1 ? pf1.v : (ks == 2 ? pf2.v : pf3.v)),
                          acc[dg]);
      }
    }
    __builtin_amdgcn_s_setprio(0);

    asm volatile("s_barrier" ::: "memory");  // D: protect KV[cur] + PL
  }

  // ---- epilogue ----
  lsum += __shfl_xor(lsum, 32);
  if (lane < 32) lex[wave * 32 + lane] = lsum;
  asm volatile("s_waitcnt lgkmcnt(0)\ns_barrier" ::: "memory");
  float linv = 1.f / (lsum + lex[(wave ^ 1) * 32 + l31]);

  // transpose through LDS: T[q 128][260 f32] (reuses KV+PL region)
  float* T = (float*)SMEM;
  {
    const int ql = wq * 32 + l31;
#pragma unroll
    for (int dg = 0; dg < 4; ++dg)
#pragma unroll
      for (int r = 0; r < 16; ++r) {
        int d = wk * 128 + dg * 32 + (r & 3) + 8 * (r >> 2) + 4 * h;
        T[ql * 260 + d] = acc[dg][r] * linv;
      }
  }
  asm volatile("s_waitcnt lgkmcnt(0)\ns_barrier" ::: "memory");

  // coalesced stores: 64 lanes cover 1KB of one row per instruction
  {
    const int rb = tid >> 6;        // 0..7
    const int c4 = (tid & 63) * 4;  // float offset
#pragma unroll
    for (int i = 0; i < 16; ++i) {
      int row = rb + i * 8;
      float4v v = *(const float4v*)(T + row * 260 + c4);
      *(float4v*)(out + ((size_t)b * Nn + q0 + row) * Dd + c4) = v;
    }
  }
}

// ---------- launch ----------
extern "C" void kernel_launch(void* const* d_in, const int* in_sizes, int n_in,
                              void* d_out, int out_size, void* d_ws, size_t ws_size,
                              hipStream_t stream) {
  const float* x = (const float*)d_in[0];
  const int* vlen = (const int*)d_in[1];
  const float* Wq = (const float*)d_in[2];
  const float* bq = (const float*)d_in[3];
  const float* Wk = (const float*)d_in[4];
  const float* bk = (const float*)d_in[5];
  const float* Wv = (const float*)d_in[6];
  const float* bv = (const float*)d_in[7];
  float* out = (float*)d_out;
  char* ws = (char*)d_ws;

  _Float16* qh = (_Float16*)(ws);
  _Float16* kk = (_Float16*)(ws + 16777216);
  _Float16* vt = (_Float16*)(ws + 33554432);
  _Float16* wh = (_Float16*)(ws + 50331648);
  _Float16* xh = (_Float16*)d_out;  // scratch; fully overwritten by k_attn

  k_split_x<<<8192, 256, 0, stream>>>(x, xh);
  k_split_w<<<768, 256, 0, stream>>>(Wq, Wk, Wv, wh);
  k_qkv<<<dim3(256, 2, 3), 256, 0, stream>>>(xh, wh, bq, bk, bv, qh, kk, vt);
  k_attn<<<256, 512, 0, stream>>>(qh, kk, vt, vlen, out);
}